// Round 1
// baseline (833.169 us; speedup 1.0000x reference)
//
#include <hip/hip_runtime.h>

#define B_ 128
#define T_ 128
#define I_ 1024
#define O_ 1024
#define M_ (B_*T_)          // 16384 rows of h
#define NOUT (M_*O_)        // 16777216 spike outputs, loss at index NOUT

// ---------------------------------------------------------------------------
// h = x @ w   (A: [M,K] row-major, B: [K,N] row-major, C: [M,N])
// 128x128 block tile, 256 threads, 8x8 micro-tile arranged as 2x2 of 4x4.
// ---------------------------------------------------------------------------
__global__ __launch_bounds__(256) void gemm_xw(const float* __restrict__ A,
                                               const float* __restrict__ Bw,
                                               float* __restrict__ C) {
    const int K = I_, N = O_;
    __shared__ float As[16][132];   // transposed A tile, padded (132*4 % 16 == 0)
    __shared__ float Bs[16][128];

    const int tid = threadIdx.x;
    const int tx = tid & 15, ty = tid >> 4;
    const int bm = blockIdx.x * 128, bn = blockIdx.y * 128;

    const int ar = tid >> 2;          // 0..63
    const int ac = (tid & 3) << 2;    // 0,4,8,12
    const int br = tid >> 5;          // 0..7
    const int bc = (tid & 31) << 2;   // 0..124

    float acc[2][2][4][4];
#pragma unroll
    for (int i = 0; i < 2; i++)
#pragma unroll
        for (int j = 0; j < 2; j++)
#pragma unroll
            for (int m = 0; m < 4; m++)
#pragma unroll
                for (int n = 0; n < 4; n++) acc[i][j][m][n] = 0.f;

    for (int k0 = 0; k0 < K; k0 += 16) {
        float4 a0 = *(const float4*)(A + (size_t)(bm + ar) * K + k0 + ac);
        float4 a1 = *(const float4*)(A + (size_t)(bm + ar + 64) * K + k0 + ac);
        float4 b0 = *(const float4*)(Bw + (size_t)(k0 + br) * N + bn + bc);
        float4 b1 = *(const float4*)(Bw + (size_t)(k0 + br + 8) * N + bn + bc);
        __syncthreads();
        As[ac + 0][ar] = a0.x; As[ac + 1][ar] = a0.y;
        As[ac + 2][ar] = a0.z; As[ac + 3][ar] = a0.w;
        As[ac + 0][ar + 64] = a1.x; As[ac + 1][ar + 64] = a1.y;
        As[ac + 2][ar + 64] = a1.z; As[ac + 3][ar + 64] = a1.w;
        *(float4*)&Bs[br][bc] = b0;
        *(float4*)&Bs[br + 8][bc] = b1;
        __syncthreads();
#pragma unroll
        for (int k = 0; k < 16; ++k) {
            float4 av0 = *(const float4*)&As[k][ty * 4];
            float4 av1 = *(const float4*)&As[k][64 + ty * 4];
            float4 bv0 = *(const float4*)&Bs[k][tx * 4];
            float4 bv1 = *(const float4*)&Bs[k][64 + tx * 4];
            float am[2][4] = {{av0.x, av0.y, av0.z, av0.w},
                              {av1.x, av1.y, av1.z, av1.w}};
            float bb[2][4] = {{bv0.x, bv0.y, bv0.z, bv0.w},
                              {bv1.x, bv1.y, bv1.z, bv1.w}};
#pragma unroll
            for (int mi = 0; mi < 2; mi++)
#pragma unroll
                for (int ni = 0; ni < 2; ni++)
#pragma unroll
                    for (int mm = 0; mm < 4; mm++)
#pragma unroll
                        for (int nn = 0; nn < 4; nn++)
                            acc[mi][ni][mm][nn] += am[mi][mm] * bb[ni][nn];
        }
    }
#pragma unroll
    for (int mi = 0; mi < 2; mi++)
#pragma unroll
        for (int mm = 0; mm < 4; mm++) {
            int m = bm + mi * 64 + ty * 4 + mm;
#pragma unroll
            for (int ni = 0; ni < 2; ni++) {
                float4 v = make_float4(acc[mi][ni][mm][0], acc[mi][ni][mm][1],
                                       acc[mi][ni][mm][2], acc[mi][ni][mm][3]);
                *(float4*)(C + (size_t)m * N + bn + ni * 64 + tx * 4) = v;
            }
        }
}

// ---------------------------------------------------------------------------
// d = w^T w   (w: [K=I_, N=O_] row-major). 64x64 tile, KT=32, 256 threads, 4x4 micro.
// ---------------------------------------------------------------------------
__global__ __launch_bounds__(256) void gemm_wtw(const float* __restrict__ W,
                                                float* __restrict__ D) {
    const int K = I_, N = O_;
    __shared__ float As[32][68];
    __shared__ float Bs[32][68];
    const int tid = threadIdx.x;
    const int tx = tid & 15, ty = tid >> 4;
    const int bj = blockIdx.x * 64, bo = blockIdx.y * 64;
    const int lr = tid >> 4;          // 0..15
    const int lc = (tid & 15) << 2;   // 0..60

    float acc[4][4];
#pragma unroll
    for (int m = 0; m < 4; m++)
#pragma unroll
        for (int n = 0; n < 4; n++) acc[m][n] = 0.f;

    for (int k0 = 0; k0 < K; k0 += 32) {
        float4 a0 = *(const float4*)(W + (size_t)(k0 + lr) * N + bj + lc);
        float4 a1 = *(const float4*)(W + (size_t)(k0 + lr + 16) * N + bj + lc);
        float4 b0 = *(const float4*)(W + (size_t)(k0 + lr) * N + bo + lc);
        float4 b1 = *(const float4*)(W + (size_t)(k0 + lr + 16) * N + bo + lc);
        __syncthreads();
        *(float4*)&As[lr][lc] = a0; *(float4*)&As[lr + 16][lc] = a1;
        *(float4*)&Bs[lr][lc] = b0; *(float4*)&Bs[lr + 16][lc] = b1;
        __syncthreads();
#pragma unroll
        for (int k = 0; k < 32; ++k) {
            float4 av = *(const float4*)&As[k][ty * 4];
            float4 bv = *(const float4*)&Bs[k][tx * 4];
            float am[4] = {av.x, av.y, av.z, av.w};
            float bb[4] = {bv.x, bv.y, bv.z, bv.w};
#pragma unroll
            for (int m = 0; m < 4; m++)
#pragma unroll
                for (int n = 0; n < 4; n++) acc[m][n] += am[m] * bb[n];
        }
    }
#pragma unroll
    for (int m = 0; m < 4; m++) {
        float4 v = make_float4(acc[m][0], acc[m][1], acc[m][2], acc[m][3]);
        *(float4*)(D + (size_t)(bj + ty * 4 + m) * N + bo + tx * 4) = v;
    }
}

// ---------------------------------------------------------------------------
// inv_norm[o] = 1 / (sum_c w[c][o]^2 + 1e-8)
// ---------------------------------------------------------------------------
__global__ void colnorm(const float* __restrict__ W, float* __restrict__ invn) {
    int o = blockIdx.x * 256 + threadIdx.x;
    float s = 0.f;
    for (int c = 0; c < I_; ++c) {
        float v = W[(size_t)c * O_ + o];
        s += v * v;
    }
    invn[o] = 1.0f / (s + 1e-8f);
}

__global__ void init_counter(unsigned int* c) { *c = 0u; }

// ---------------------------------------------------------------------------
// Sequential scan: one block per batch sample. 256 threads x 4 neurons each.
// Spikes are sparse -> keep a compact index list in LDS (ping-pong), and
// rst = sum of listed rows of d.
// ---------------------------------------------------------------------------
__global__ __launch_bounds__(256) void scan_kernel(const float* __restrict__ h,
                                                   const float* __restrict__ d,
                                                   const float* __restrict__ invn,
                                                   const float* __restrict__ bias,
                                                   const float* __restrict__ beta,
                                                   float* __restrict__ out,
                                                   unsigned int* __restrict__ spike_count) {
    __shared__ int lst[2][O_];
    __shared__ int cnt[2];
    __shared__ unsigned int red[256];

    const int tid = threadIdx.x;
    const int b = blockIdx.x;
    const float betav = beta[0];
    const float omb = 1.0f - betav;

    float mem[4] = {0.f, 0.f, 0.f, 0.f};
    float invnl[4], bl[4];
    int o[4];
#pragma unroll
    for (int k = 0; k < 4; k++) {
        o[k] = tid + 256 * k;
        invnl[k] = invn[o[k]];
        bl[k] = bias[o[k]];
    }
    if (tid < 2) cnt[tid] = 0;
    unsigned int local_count = 0;
    const float* hb = h + (size_t)b * T_ * O_;
    float* ob = out + (size_t)b * T_ * O_;
    __syncthreads();

    for (int t = 0; t < T_; ++t) {
        const int p = t & 1, q = p ^ 1;
        const int n = cnt[p];
        __syncthreads();                 // everyone has read n
        if (tid == 0) cnt[p] = 0;        // ready for appends at step t+1

        float rst[4] = {0.f, 0.f, 0.f, 0.f};
        for (int i = 0; i < n; ++i) {
            const int j = lst[p][i];     // block-uniform -> LDS broadcast
            const float* drow = d + (size_t)j * O_;
#pragma unroll
            for (int k = 0; k < 4; k++) rst[k] += drow[o[k]];
        }
#pragma unroll
        for (int k = 0; k < 4; k++) {
            float ht = hb[t * O_ + o[k]];
            mem[k] = (mem[k] - rst[k]) * betav + ht * omb;
            float mthr = mem[k] * invnl[k] - bl[k];
            int s = mthr > 0.0f;
            ob[t * O_ + o[k]] = s ? 1.0f : 0.0f;
            local_count += (unsigned)s;
            if (s) {
                int pos = atomicAdd(&cnt[q], 1);
                lst[q][pos] = o[k];
            }
        }
        __syncthreads();                 // appends visible for next gather
    }

    // block reduction of spike count
    red[tid] = local_count;
    __syncthreads();
    for (int s = 128; s > 0; s >>= 1) {
        if (tid < s) red[tid] += red[tid + s];
        __syncthreads();
    }
    if (tid == 0) atomicAdd(spike_count, red[0]);
}

__global__ void finalize_loss(const unsigned int* __restrict__ spike_count,
                              float* __restrict__ loss_out) {
    // count <= 2^24 so float is exact; /2^24 and *0.5 are exact scalings
    *loss_out = 0.5f * ((float)(*spike_count) / 16777216.0f);
}

// ---------------------------------------------------------------------------
extern "C" void kernel_launch(void* const* d_in, const int* in_sizes, int n_in,
                              void* d_out, int out_size, void* d_ws, size_t ws_size,
                              hipStream_t stream) {
    const float* x    = (const float*)d_in[0];   // [B,T,I]
    const float* w    = (const float*)d_in[1];   // [I,O]
    const float* beta = (const float*)d_in[2];   // [1]
    const float* bias = (const float*)d_in[3];   // [O]
    float* out = (float*)d_out;                  // NOUT spikes + 1 loss

    // workspace layout
    char* ws = (char*)d_ws;
    float* h    = (float*)ws;                                   // 64 MiB
    float* dmat = (float*)(ws + (size_t)67108864);              // 4 MiB
    float* invn = (float*)(ws + (size_t)67108864 + 4194304);    // 4 KiB
    unsigned int* cntp = (unsigned int*)(ws + (size_t)67108864 + 4194304 + 4096);

    gemm_xw<<<dim3(M_ / 128, O_ / 128), 256, 0, stream>>>(x, w, h);
    gemm_wtw<<<dim3(O_ / 64, O_ / 64), 256, 0, stream>>>(w, dmat);
    colnorm<<<O_ / 256, 256, 0, stream>>>(w, invn);
    init_counter<<<1, 1, 0, stream>>>(cntp);
    scan_kernel<<<B_, 256, 0, stream>>>(h, dmat, invn, bias, beta, out, cntp);
    finalize_loss<<<1, 1, 0, stream>>>(cntp, out + (size_t)NOUT);
}